// Round 13
// baseline (214.510 us; speedup 1.0000x reference)
//
#include <hip/hip_runtime.h>

// 21-qubit statevector policy net — per-phase kernels.
// R13: GB=512, one 32KB tile per block, 2 blocks/CU (cross-block overlap fills
// intra-block serial-chain stalls). B pass = R10/R11 half algebra with the half
// index H promoted to a block bit (blkB = blk>>1, H = blk&1). A pass = verbatim
// R7 single-tile + R12 load hoisting + layer-3 measurement/final fold.
// ws: psi (2^21 float2, 16MB) | partials (512*22 f32) @16MB | done @16MB+48K
#define NQ 21
#define DIM (1 << NQ)
#define NL 4
#define ADIM 18
#define GB 512   // blocks per pass (2 per CU)
#define NT 512

__device__ __forceinline__ float2 cfma2(float2 u0, float2 a, float2 u1, float2 b) {
    return make_float2(u0.x * a.x - u0.y * a.y + u1.x * b.x - u1.y * b.y,
                       u0.x * a.y + u0.y * a.x + u1.x * b.y + u1.y * b.x);
}

struct GateU { float2 u00, u01, u10, u11; };

__device__ __forceinline__ void bfly(float2& a, float2& b, const GateU& U) {
    float2 na = cfma2(U.u00, a, U.u01, b);
    float2 nb = cfma2(U.u10, a, U.u11, b);
    a = na; b = nb;
}

// LDS bank swizzle (verified R6/R7/R10)
__device__ __forceinline__ int sw(int j) { return j ^ (((j >> 4) & 7) << 1); }

// sc0 sc1 = LLC-coherent, XCD-L2 bypass (verified R9)
__device__ __forceinline__ void store4_sc(float* p, float v) {
    asm volatile("global_store_dword %0, %1, off sc0 sc1" :: "v"(p), "v"(v) : "memory");
}
__device__ __forceinline__ float load_sc_f(const float* p) {
    float r;
    asm volatile("global_load_dword %0, %1, off sc0 sc1\n\ts_waitcnt vmcnt(0)"
                 : "=v"(r) : "v"(p) : "memory");
    return r;
}
__device__ __forceinline__ void drain_vmem() {
    asm volatile("s_waitcnt vmcnt(0)" ::: "memory");
}

// threads 0..20: fused U = RZ*RY*RX for this layer
__device__ __forceinline__ void make_mats(GateU* mats, const float* __restrict__ cp, int layer, int tid) {
    if (tid < NQ) {
        const float* ang = cp + (layer * NQ + tid) * 3;
        float a = ang[0], b = ang[1], c = ang[2];
        float ca = cosf(0.5f * a), sa = sinf(0.5f * a);
        float cb = cosf(0.5f * b), sb = sinf(0.5f * b);
        float cc = cosf(0.5f * c), sc = sinf(0.5f * c);
        float2 m00 = make_float2(cb * ca,  sb * sa);
        float2 m01 = make_float2(-sb * ca, -cb * sa);
        float2 m10 = make_float2(sb * ca,  -cb * sa);
        float2 m11 = make_float2(cb * ca,  -sb * sa);
        GateU U;
        U.u00 = make_float2(cc * m00.x + sc * m00.y, cc * m00.y - sc * m00.x);
        U.u01 = make_float2(cc * m01.x + sc * m01.y, cc * m01.y - sc * m01.x);
        U.u10 = make_float2(cc * m10.x - sc * m10.y, cc * m10.y + sc * m10.x);
        U.u11 = make_float2(cc * m11.x - sc * m11.y, cc * m11.y + sc * m11.x);
        mats[tid] = U;
    }
}

// radix-8 round: 3 gates per LDS round-trip (verified R7)
__device__ __forceinline__ void round3(float2* tile, int tid, int g,
                                       GateU Ua, GateU Ub, GateU Uc) {
    int bl = (1 << g) - 1;
    int base = (tid & bl) | ((tid >> g) << (g + 3));
    float2 v[8];
#pragma unroll
    for (int j = 0; j < 8; ++j) v[j] = tile[sw(base + (j << g))];
#pragma unroll
    for (int s = 0; s < 8; s += 2) bfly(v[s], v[s + 1], Ua);
#pragma unroll
    for (int s = 0; s < 8; ++s) if (!(s & 2)) bfly(v[s], v[s | 2], Ub);
#pragma unroll
    for (int s = 0; s < 8; ++s) if (!(s & 4)) bfly(v[s], v[s | 4], Uc);
#pragma unroll
    for (int j = 0; j < 8; ++j) tile[sw(base + (j << g))] = v[j];
    __syncthreads();
}

// ===== B pass (verified R10/R11 algebra, H as block bit): complex idx =
// (h<<12)|(blkB<<4)|(H<<3)|(l&7); h = bits 12..20 (qubits 0..8), blkB = bits 4..11,
// H = bit 3, slot = (h<<3)|(l&7). One 32KB tile per block.
__global__ __launch_bounds__(NT, 4) void k_passB(const float* __restrict__ state,
                                                 float2* __restrict__ psi,
                                                 const float* __restrict__ cp, int layer,
                                                 int* __restrict__ done) {
    __shared__ float2 tile[4096];
    __shared__ GateU mats[NQ];
    const int tid = threadIdx.x, blk = blockIdx.x;
    const int blkB = blk >> 1, H = blk & 1;
    float4* psi4 = (float4*)psi;
    const int srcmask = (layer < 3) ? 0xFF : 0;

    make_mats(mats, cp, layer, tid);
    if (layer == 0 && blk == 0 && tid == 32) *done = 0;   // for A3's last-block fold
    __syncthreads();

    if (layer == 0) {
        const float4* s4 = (const float4*)state;
        float4 w[2];
        for (int i = 0; i < 2; ++i) {
            int f = i * NT + tid, d = f & 1, h = f >> 1;
            w[i] = s4[(h << 10) | (blkB << 2) | (2 * H + d)];
        }
        float4* t4 = (float4*)tile;
        for (int i = 0; i < 2; ++i) {
            int f = i * NT + tid, d = f & 1, h = f >> 1;
            int j = (h << 3) | (4 * d);
            t4[sw(j) >> 1]     = make_float4(w[i].x, 0.f, w[i].y, 0.f);
            t4[sw(j + 2) >> 1] = make_float4(w[i].z, 0.f, w[i].w, 0.f);
        }
    } else {
        float4 w[4];
        for (int i = 0; i < 4; ++i) {
            int f = i * NT + tid, c = f & 3, h = f >> 2;
            w[i] = psi4[(h << 11) | (blkB << 3) | (4 * H + c)];
        }
        for (int i = 0; i < 4; ++i) {
            int f = i * NT + tid, c = f & 3, h = f >> 2;
            int se = (h << 3) | (2 * c);
            // c4 (prev layer's CNOT ctrl q20 -> tgt q0): l odd => flip bit 20 = slot bit 11
            tile[sw(se)]              = make_float2(w[i].x, w[i].y);
            tile[sw((se + 1) ^ 2048)] = make_float2(w[i].z, w[i].w);
        }
    }
    __syncthreads();
    round3(tile, tid, 3, mats[8], mats[7], mats[6]);   // q8,q7,q6
    round3(tile, tid, 6, mats[5], mats[4], mats[3]);   // q5,q4,q3
    round3(tile, tid, 9, mats[2], mats[1], mats[0]);   // q2,q1,q0
    // store: B-local CNOT chain as gather: src h = h ^ ((h>>1)&mask)
    for (int i = 0; i < 4; ++i) {
        int f = i * NT + tid, c = f & 3, h = f >> 2;
        int hs = h ^ ((h >> 1) & srcmask);
        int s = (hs << 3) | (2 * c);
        float2 e0 = tile[sw(s)], e1 = tile[sw(s + 1)];
        psi4[(h << 11) | (blkB << 3) | (4 * H + c)] = make_float4(e0.x, e0.y, e1.x, e1.y);
    }
}

// A pass helpers (verbatim R7/R11)
__device__ __forceinline__ void a_regscatter(float2* tile, const float4* w,
                                             const GateU* mats, int tid) {
    float2 v[8];
    float4* t4 = (float4*)tile;
#pragma unroll
    for (int i = 0; i < 4; ++i) {
        v[2 * i]     = make_float2(w[i].x, w[i].y);
        v[2 * i + 1] = make_float2(w[i].z, w[i].w);
    }
    GateU U20 = mats[20];
#pragma unroll
    for (int s = 0; s < 8; s += 2) bfly(v[s], v[s + 1], U20);
    GateU U10 = mats[10];
#pragma unroll
    for (int s = 0; s < 8; ++s) if (!(s & 2)) bfly(v[s], v[s | 2], U10);
    GateU U9 = mats[9];
#pragma unroll
    for (int s = 0; s < 8; ++s) if (!(s & 4)) bfly(v[s], v[s | 4], U9);
    for (int i = 0; i < 4; ++i)
        t4[sw(2 * (i * NT + tid)) >> 1] =
            make_float4(v[2 * i].x, v[2 * i].y, v[2 * i + 1].x, v[2 * i + 1].y);
}

__device__ __forceinline__ void a_rounds(float2* tile, const GateU* mats, int tid) {
    round3(tile, tid, 1, mats[19], mats[18], mats[17]);
    round3(tile, tid, 4, mats[16], mats[15], mats[14]);
    round3(tile, tid, 7, mats[13], mats[12], mats[11]);
}

// A pass: bits 0..11 local (qubits 9..20); block = tile = bits 12..20.
// Layer 3: measurement + last-block final (head+softmax) folded in.
__global__ __launch_bounds__(NT, 4) void k_passA(float2* __restrict__ psi,
                                                 const float* __restrict__ cp, int layer,
                                                 float* __restrict__ partials,
                                                 const float* __restrict__ head_w,
                                                 const float* __restrict__ head_b,
                                                 float* __restrict__ out,
                                                 int* __restrict__ done) {
    __shared__ float2 tile[4096];
    __shared__ GateU mats[NQ];
    __shared__ float red2[640];
    __shared__ float meas[NQ];
    __shared__ float lg[ADIM];
    __shared__ int lastflag;
    const int tid = threadIdx.x, blk = blockIdx.x;
    float4* psi4 = (float4*)psi;

    make_mats(mats, cp, layer, tid);
    __syncthreads();

    float4 w[4];
    {
        const float4* ga = psi4 + (size_t)blk * 2048;
        for (int i = 0; i < 4; ++i) w[i] = ga[i * NT + tid];
    }
    a_regscatter(tile, w, mats, tid);
    __syncthreads();
    a_rounds(tile, mats, tid);

    if (layer < 3) {
        // boundary CNOT (ctrl = stored bit12 = blk&1, tgt bit11) + A-local chain, as gather
        float4* oa = psi4 + (size_t)blk * 2048;
        int cb = (blk & 1) << 11;
        for (int i = 0; i < 4; ++i) {
            int f = i * NT + tid;
            int s0 = ((2 * f) ^ (f & 0x7FF)) ^ cb;
            float2 e0 = tile[sw(s0)], e1 = tile[sw(s0 ^ 1)];
            oa[f] = make_float4(e0.x, e0.y, e1.x, e1.y);
        }
    } else {
        // measurement: total + per-qubit ones sums
        float tot = 0.f, ones[NQ];
#pragma unroll
        for (int q = 0; q < NQ; ++q) ones[q] = 0.f;
        for (int it = 0; it < 8; ++it) {
            int j = it * NT + tid;
            float2 a2 = tile[sw(j)];
            float pr = a2.x * a2.x + a2.y * a2.y;
            int gidx = (blk << 12) | j;
            tot += pr;
#pragma unroll
            for (int q = 0; q < NQ; ++q)
                ones[q] += pr * (float)((gidx >> (20 - q)) & 1);
        }
        for (int off = 32; off; off >>= 1) {
            tot += __shfl_down(tot, off, 64);
#pragma unroll
            for (int q = 0; q < NQ; ++q) ones[q] += __shfl_down(ones[q], off, 64);
        }
        __syncthreads();
        float* red = (float*)tile;
        int wv = tid >> 6, ln = tid & 63;
        if (ln == 0) {
            red[wv * 22 + 21] = tot;
#pragma unroll
            for (int q = 0; q < NQ; ++q) red[wv * 22 + q] = ones[q];
        }
        __syncthreads();
        if (tid < 22) {
            float s = 0.f;
            for (int wvi = 0; wvi < 8; ++wvi) s += red[wvi * 22 + tid];
            store4_sc(&partials[blk * 22 + tid], s);
        }
        drain_vmem();
        __syncthreads();
        if (tid == 0) lastflag = (atomicAdd(done, 1) == GB - 1);
        __syncthreads();
        if (!lastflag) return;

        // last block: reduce 512 partial rows (sc) -> meas -> head -> softmax
        int col = tid % 22, grp = tid / 22;
        if (tid < 506) {
            float s = 0.f;
            for (int r = grp; r < GB; r += 23) s += load_sc_f(&partials[r * 22 + col]);
            red2[grp * 22 + col] = s;
        }
        __syncthreads();
        if (tid < 22) {
            float t2 = 0.f;
            for (int g = 0; g < 23; ++g) t2 += red2[g * 22 + tid];
            red2[600 + tid] = t2;
        }
        __syncthreads();
        if (tid < NQ) {
            float tt = red2[600 + 21];
            meas[tid] = (tt > 0.f) ? (1.f - 2.f * red2[600 + tid] / tt) : 1.f;
        }
        __syncthreads();
        if (tid < ADIM) {
            float s2 = head_b[tid];
            for (int q = 0; q < NQ; ++q) s2 += head_w[tid * NQ + q] * meas[q];
            lg[tid] = s2;
        }
        __syncthreads();
        if (tid == 0) {
            float m = lg[0];
            for (int a = 1; a < ADIM; ++a) m = fmaxf(m, lg[a]);
            float ssum = 0.f;
            for (int a = 0; a < ADIM; ++a) ssum += expf(lg[a] - m);
            float inv = 1.f / ssum;
            for (int a = 0; a < ADIM; ++a) out[a] = expf(lg[a] - m) * inv;
        }
    }
}

extern "C" void kernel_launch(void* const* d_in, const int* in_sizes, int n_in,
                              void* d_out, int out_size, void* d_ws, size_t ws_size,
                              hipStream_t stream) {
    const float* state   = (const float*)d_in[0];
    const float* cparams = (const float*)d_in[1];
    const float* head_w  = (const float*)d_in[2];
    const float* head_b  = (const float*)d_in[3];
    float* out = (float*)d_out;

    char* ws = (char*)d_ws;
    float2* psi      = (float2*)ws;
    float*  partials = (float*)(ws + (size_t)DIM * 8);
    int*    done     = (int*)(ws + (size_t)DIM * 8 + 49152);

    for (int layer = 0; layer < NL; ++layer) {
        k_passB<<<GB, NT, 0, stream>>>(state, psi, cparams, layer, done);
        k_passA<<<GB, NT, 0, stream>>>(psi, cparams, layer, partials,
                                       head_w, head_b, out, done);
    }
}

// Round 14
// 196.948 us; speedup vs baseline: 1.0892x; 1.0892x over previous
//
#include <hip/hip_runtime.h>

// 21-qubit statevector policy net — per-phase kernels, software-pipelined.
// R14 = revert to R12 (best measured: 196.6 µs). R13's 2-blocks/CU split regressed
// (doubled per-block fixed cost, lost intra-block dual-tile pipelining).
// ws: psi (2^21 float2, 16MB) | partials (256*22 f32) @16MB | done @16MB+32K
#define NQ 21
#define DIM (1 << NQ)
#define NL 4
#define ADIM 18
#define GB 256   // blocks per pass
#define NT 512

__device__ __forceinline__ float2 cfma2(float2 u0, float2 a, float2 u1, float2 b) {
    return make_float2(u0.x * a.x - u0.y * a.y + u1.x * b.x - u1.y * b.y,
                       u0.x * a.y + u0.y * a.x + u1.x * b.y + u1.y * b.x);
}

struct GateU { float2 u00, u01, u10, u11; };

__device__ __forceinline__ void bfly(float2& a, float2& b, const GateU& U) {
    float2 na = cfma2(U.u00, a, U.u01, b);
    float2 nb = cfma2(U.u10, a, U.u11, b);
    a = na; b = nb;
}

// LDS bank swizzle (verified R6/R7/R10)
__device__ __forceinline__ int sw(int j) { return j ^ (((j >> 4) & 7) << 1); }

// sc0 sc1 = LLC-coherent, XCD-L2 bypass (verified R9)
__device__ __forceinline__ void store4_sc(float* p, float v) {
    asm volatile("global_store_dword %0, %1, off sc0 sc1" :: "v"(p), "v"(v) : "memory");
}
__device__ __forceinline__ float load_sc_f(const float* p) {
    float r;
    asm volatile("global_load_dword %0, %1, off sc0 sc1\n\ts_waitcnt vmcnt(0)"
                 : "=v"(r) : "v"(p) : "memory");
    return r;
}
__device__ __forceinline__ void drain_vmem() {
    asm volatile("s_waitcnt vmcnt(0)" ::: "memory");
}

// threads 0..20: fused U = RZ*RY*RX for this layer
__device__ __forceinline__ void make_mats(GateU* mats, const float* __restrict__ cp, int layer, int tid) {
    if (tid < NQ) {
        const float* ang = cp + (layer * NQ + tid) * 3;
        float a = ang[0], b = ang[1], c = ang[2];
        float ca = cosf(0.5f * a), sa = sinf(0.5f * a);
        float cb = cosf(0.5f * b), sb = sinf(0.5f * b);
        float cc = cosf(0.5f * c), sc = sinf(0.5f * c);
        float2 m00 = make_float2(cb * ca,  sb * sa);
        float2 m01 = make_float2(-sb * ca, -cb * sa);
        float2 m10 = make_float2(sb * ca,  -cb * sa);
        float2 m11 = make_float2(cb * ca,  -sb * sa);
        GateU U;
        U.u00 = make_float2(cc * m00.x + sc * m00.y, cc * m00.y - sc * m00.x);
        U.u01 = make_float2(cc * m01.x + sc * m01.y, cc * m01.y - sc * m01.x);
        U.u10 = make_float2(cc * m10.x - sc * m10.y, cc * m10.y + sc * m10.x);
        U.u11 = make_float2(cc * m11.x - sc * m11.y, cc * m11.y + sc * m11.x);
        mats[tid] = U;
    }
}

// radix-8 round: 3 gates per LDS round-trip (verified R7)
__device__ __forceinline__ void round3(float2* tile, int tid, int g,
                                       GateU Ua, GateU Ub, GateU Uc) {
    int bl = (1 << g) - 1;
    int base = (tid & bl) | ((tid >> g) << (g + 3));
    float2 v[8];
#pragma unroll
    for (int j = 0; j < 8; ++j) v[j] = tile[sw(base + (j << g))];
#pragma unroll
    for (int s = 0; s < 8; s += 2) bfly(v[s], v[s + 1], Ua);
#pragma unroll
    for (int s = 0; s < 8; ++s) if (!(s & 2)) bfly(v[s], v[s | 2], Ub);
#pragma unroll
    for (int s = 0; s < 8; ++s) if (!(s & 4)) bfly(v[s], v[s | 4], Uc);
#pragma unroll
    for (int j = 0; j < 8; ++j) tile[sw(base + (j << g))] = v[j];
    __syncthreads();
}

// ===== B pass (verified R10/R11 algebra): complex idx = (h<<12)|(blk<<4)|l; h = bits 12..20
// (9 bits, qubits 0..8), blk = bits 4..11, l = bits 0..3. Two l-halves, dual LDS buffers.
__global__ __launch_bounds__(NT, 2) void k_passB(const float* __restrict__ state,
                                                 float2* __restrict__ psi,
                                                 const float* __restrict__ cp, int layer,
                                                 int* __restrict__ done) {
    __shared__ float2 tA[4096], tB[4096];
    __shared__ GateU mats[NQ];
    const int tid = threadIdx.x, blk = blockIdx.x;
    float4* psi4 = (float4*)psi;
    const int srcmask = (layer < 3) ? 0xFF : 0;

    // mats FIRST, then its barrier, so later syncs don't drain hoisted loads at vmcnt(0)
    make_mats(mats, cp, layer, tid);
    if (layer == 0 && blk == 0 && tid == 32) *done = 0;   // for A3's last-block fold
    __syncthreads();

    float4 wA[4], wB[4];
    if (layer == 0) {
        const float4* s4 = (const float4*)state;
        for (int i = 0; i < 2; ++i) {
            int f = i * NT + tid, d = f & 1, h = f >> 1;
            wA[i] = s4[(h << 10) | (blk << 2) | d];
            wB[i] = s4[(h << 10) | (blk << 2) | (2 + d)];
        }
    } else {
        for (int i = 0; i < 4; ++i) {
            int f = i * NT + tid, c = f & 3, h = f >> 2;
            wA[i] = psi4[(h << 11) | (blk << 3) | c];
            wB[i] = psi4[(h << 11) | (blk << 3) | (4 + c)];
        }
    }

    // scatter half 0 -> tA (uses wA only; wB still in flight)
    if (layer == 0) {
        float4* t4 = (float4*)tA;
        for (int i = 0; i < 2; ++i) {
            int f = i * NT + tid, d = f & 1, h = f >> 1;
            int j = (h << 3) | (4 * d);
            float4 w = wA[i];
            t4[sw(j) >> 1]     = make_float4(w.x, 0.f, w.y, 0.f);
            t4[sw(j + 2) >> 1] = make_float4(w.z, 0.f, w.w, 0.f);
        }
    } else {
        for (int i = 0; i < 4; ++i) {
            int f = i * NT + tid, c = f & 3, h = f >> 2;
            int se = (h << 3) | (2 * c);
            float4 w = wA[i];
            // c4 (prev layer's CNOT ctrl q20 -> tgt q0): l odd => flip bit 20 = slot bit 11
            tA[sw(se)]              = make_float2(w.x, w.y);
            tA[sw((se + 1) ^ 2048)] = make_float2(w.z, w.w);
        }
    }
    __syncthreads();
    round3(tA, tid, 3, mats[8], mats[7], mats[6]);
    round3(tA, tid, 6, mats[5], mats[4], mats[3]);
    round3(tA, tid, 9, mats[2], mats[1], mats[0]);

    // store half 0 (chain gather: src h = h ^ ((h>>1)&mask)) + scatter half 1 -> tB
    for (int i = 0; i < 4; ++i) {
        int f = i * NT + tid, c = f & 3, h = f >> 2;
        int hs = h ^ ((h >> 1) & srcmask);
        int s = (hs << 3) | (2 * c);
        float2 e0 = tA[sw(s)], e1 = tA[sw(s + 1)];
        psi4[(h << 11) | (blk << 3) | c] = make_float4(e0.x, e0.y, e1.x, e1.y);
    }
    if (layer == 0) {
        float4* t4 = (float4*)tB;
        for (int i = 0; i < 2; ++i) {
            int f = i * NT + tid, d = f & 1, h = f >> 1;
            int j = (h << 3) | (4 * d);
            float4 w = wB[i];
            t4[sw(j) >> 1]     = make_float4(w.x, 0.f, w.y, 0.f);
            t4[sw(j + 2) >> 1] = make_float4(w.z, 0.f, w.w, 0.f);
        }
    } else {
        for (int i = 0; i < 4; ++i) {
            int f = i * NT + tid, c = f & 3, h = f >> 2;
            int se = (h << 3) | (2 * c);
            float4 w = wB[i];
            tB[sw(se)]              = make_float2(w.x, w.y);
            tB[sw((se + 1) ^ 2048)] = make_float2(w.z, w.w);
        }
    }
    __syncthreads();
    round3(tB, tid, 3, mats[8], mats[7], mats[6]);
    round3(tB, tid, 6, mats[5], mats[4], mats[3]);
    round3(tB, tid, 9, mats[2], mats[1], mats[0]);
    for (int i = 0; i < 4; ++i) {
        int f = i * NT + tid, c = f & 3, h = f >> 2;
        int hs = h ^ ((h >> 1) & srcmask);
        int s = (hs << 3) | (2 * c);
        float2 e0 = tB[sw(s)], e1 = tB[sw(s + 1)];
        psi4[(h << 11) | (blk << 3) | (4 + c)] = make_float4(e0.x, e0.y, e1.x, e1.y);
    }
}

// regscatter for A pass (verbatim R7/R10): reg gates q20,q10,q9 then LDS scatter
__device__ __forceinline__ void a_regscatter(float2* tile, const float4* w,
                                             const GateU* mats, int tid) {
    float2 v[8];
    float4* t4 = (float4*)tile;
#pragma unroll
    for (int i = 0; i < 4; ++i) {
        v[2 * i]     = make_float2(w[i].x, w[i].y);
        v[2 * i + 1] = make_float2(w[i].z, w[i].w);
    }
    GateU U20 = mats[20];
#pragma unroll
    for (int s = 0; s < 8; s += 2) bfly(v[s], v[s + 1], U20);
    GateU U10 = mats[10];
#pragma unroll
    for (int s = 0; s < 8; ++s) if (!(s & 2)) bfly(v[s], v[s | 2], U10);
    GateU U9 = mats[9];
#pragma unroll
    for (int s = 0; s < 8; ++s) if (!(s & 4)) bfly(v[s], v[s | 4], U9);
    for (int i = 0; i < 4; ++i)
        t4[sw(2 * (i * NT + tid)) >> 1] =
            make_float4(v[2 * i].x, v[2 * i].y, v[2 * i + 1].x, v[2 * i + 1].y);
}

__device__ __forceinline__ void a_rounds(float2* tile, const GateU* mats, int tid) {
    round3(tile, tid, 1, mats[19], mats[18], mats[17]);
    round3(tile, tid, 4, mats[16], mats[15], mats[14]);
    round3(tile, tid, 7, mats[13], mats[12], mats[11]);
}

// gather-store with boundary CNOT + A-local chain (verbatim R7)
__device__ __forceinline__ void a_gatherstore(float2* tile, float4* oa, int t, int tid) {
    int cb = (t & 1) << 11;
    for (int i = 0; i < 4; ++i) {
        int f = i * NT + tid;
        int s0 = ((2 * f) ^ (f & 0x7FF)) ^ cb;
        float2 e0 = tile[sw(s0)], e1 = tile[sw(s0 ^ 1)];
        oa[f] = make_float4(e0.x, e0.y, e1.x, e1.y);
    }
}

__device__ __forceinline__ void a_accum(float2* tile, int t, int tid,
                                        float& tot, float* ones) {
    for (int it = 0; it < 8; ++it) {
        int j = it * NT + tid;
        float2 a2 = tile[sw(j)];
        float pr = a2.x * a2.x + a2.y * a2.y;
        int gidx = (t << 12) | j;
        tot += pr;
#pragma unroll
        for (int q = 0; q < NQ; ++q)
            ones[q] += pr * (float)((gidx >> (20 - q)) & 1);
    }
}

// A pass: bits 0..11 local (qubits 9..20); tiles t0=2blk, t1=2blk+1 pipelined.
// Layer 3: measurement + last-block-done final (head+softmax) folded in.
__global__ __launch_bounds__(NT, 2) void k_passA(float2* __restrict__ psi,
                                                 const float* __restrict__ cp, int layer,
                                                 float* __restrict__ partials,
                                                 const float* __restrict__ head_w,
                                                 const float* __restrict__ head_b,
                                                 float* __restrict__ out,
                                                 int* __restrict__ done) {
    __shared__ float2 tA[4096], tB[4096];
    __shared__ GateU mats[NQ];
    __shared__ float meas[NQ];
    __shared__ float lg[ADIM];
    __shared__ int lastflag;
    const int tid = threadIdx.x, blk = blockIdx.x;
    float4* psi4 = (float4*)psi;
    const int t0 = 2 * blk, t1 = 2 * blk + 1;

    make_mats(mats, cp, layer, tid);
    __syncthreads();

    float4 w0[4], w1[4];
    {
        const float4* ga0 = psi4 + (size_t)t0 * 2048;
        const float4* ga1 = psi4 + (size_t)t1 * 2048;
        for (int i = 0; i < 4; ++i) w0[i] = ga0[i * NT + tid];
        for (int i = 0; i < 4; ++i) w1[i] = ga1[i * NT + tid];
    }

    a_regscatter(tA, w0, mats, tid);
    __syncthreads();
    a_rounds(tA, mats, tid);

    if (layer < 3) {
        a_gatherstore(tA, psi4 + (size_t)t0 * 2048, t0, tid);   // overlaps t1 compute
        a_regscatter(tB, w1, mats, tid);
        __syncthreads();
        a_rounds(tB, mats, tid);
        a_gatherstore(tB, psi4 + (size_t)t1 * 2048, t1, tid);
    } else {
        float tot = 0.f, ones[NQ];
#pragma unroll
        for (int q = 0; q < NQ; ++q) ones[q] = 0.f;
        a_accum(tA, t0, tid, tot, ones);
        a_regscatter(tB, w1, mats, tid);
        __syncthreads();
        a_rounds(tB, mats, tid);
        a_accum(tB, t1, tid, tot, ones);

        for (int off = 32; off; off >>= 1) {
            tot += __shfl_down(tot, off, 64);
#pragma unroll
            for (int q = 0; q < NQ; ++q) ones[q] += __shfl_down(ones[q], off, 64);
        }
        __syncthreads();
        float* red = (float*)tA;
        int wv = tid >> 6, ln = tid & 63;
        if (ln == 0) {
            red[wv * 22 + 21] = tot;
#pragma unroll
            for (int q = 0; q < NQ; ++q) red[wv * 22 + q] = ones[q];
        }
        __syncthreads();
        if (tid < 22) {
            float s = 0.f;
            for (int wvi = 0; wvi < 8; ++wvi) s += red[wvi * 22 + tid];
            store4_sc(&partials[blk * 22 + tid], s);
        }
        drain_vmem();
        __syncthreads();
        if (tid == 0) lastflag = (atomicAdd(done, 1) == GB - 1);
        __syncthreads();
        if (!lastflag) return;

        // last block: reduce 256 partial rows (sc) -> meas -> head -> softmax
        float* red2 = (float*)tB;
        int col = tid % 22, grp = tid / 22;
        if (tid < 506) {
            float s = 0.f;
            for (int r = grp; r < GB; r += 23) s += load_sc_f(&partials[r * 22 + col]);
            red2[grp * 22 + col] = s;
        }
        __syncthreads();
        if (tid < 22) {
            float t2 = 0.f;
            for (int g = 0; g < 23; ++g) t2 += red2[g * 22 + tid];
            red2[600 + tid] = t2;
        }
        __syncthreads();
        if (tid < NQ) {
            float tt = red2[600 + 21];
            meas[tid] = (tt > 0.f) ? (1.f - 2.f * red2[600 + tid] / tt) : 1.f;
        }
        __syncthreads();
        if (tid < ADIM) {
            float s2 = head_b[tid];
            for (int q = 0; q < NQ; ++q) s2 += head_w[tid * NQ + q] * meas[q];
            lg[tid] = s2;
        }
        __syncthreads();
        if (tid == 0) {
            float m = lg[0];
            for (int a = 1; a < ADIM; ++a) m = fmaxf(m, lg[a]);
            float ssum = 0.f;
            for (int a = 0; a < ADIM; ++a) ssum += expf(lg[a] - m);
            float inv = 1.f / ssum;
            for (int a = 0; a < ADIM; ++a) out[a] = expf(lg[a] - m) * inv;
        }
    }
}

extern "C" void kernel_launch(void* const* d_in, const int* in_sizes, int n_in,
                              void* d_out, int out_size, void* d_ws, size_t ws_size,
                              hipStream_t stream) {
    const float* state   = (const float*)d_in[0];
    const float* cparams = (const float*)d_in[1];
    const float* head_w  = (const float*)d_in[2];
    const float* head_b  = (const float*)d_in[3];
    float* out = (float*)d_out;

    char* ws = (char*)d_ws;
    float2* psi      = (float2*)ws;
    float*  partials = (float*)(ws + (size_t)DIM * 8);
    int*    done     = (int*)(ws + (size_t)DIM * 8 + 32768);

    for (int layer = 0; layer < NL; ++layer) {
        k_passB<<<GB, NT, 0, stream>>>(state, psi, cparams, layer, done);
        k_passA<<<GB, NT, 0, stream>>>(psi, cparams, layer, partials,
                                       head_w, head_b, out, done);
    }
}